// Round 1
// baseline (178.611 us; speedup 1.0000x reference)
//
#include <hip/hip_runtime.h>

// WaveletFeatureExtractor: db4 wavedec (5 levels, symmetric pad) -> adaptive pool 128
// -> per-level 128x128 MLP (ReLU) -> fused 640->512 MLP (ReLU).
//
// Kernel 1 (dwt_pool): one block per batch row. Level 1 computed straight from
// global (only low-pass needed; cD1 is unused by the reference forward). Levels
// 2..5 run entirely in LDS with ping-pong cA buffers; each cD band is pooled to
// 128 segment means and written to d_ws as pooled[row][level*128 + p].
// Kernel 2 (mlp): 8 rows per block; per-level feats into LDS, then fusion GEMM,
// with 8-row accumulator blocking so each weight load is reused 8x.

#define BATCH   2048
#define SIGLEN  16384
#define N1      8195
#define N2      4101
#define N3      2054
#define N4      1030
#define N5      518
#define POOLP   128
#define COMB    640   // 5 * 128
#define OUTD    512

// Reversed db4 decomposition filters (reference flips filt[:, ::-1] -> correlation)
__constant__ float LO_R[8] = {
     0.2303778133088965f,   0.7148465705529157f,   0.6308807679298589f,
    -0.027983769416859854f, -0.18703481171909309f,  0.030841381835560764f,
     0.0328830116668852f,  -0.010597401785069032f };
__constant__ float HI_R[8] = {
    -0.010597401785069032f, -0.0328830116668852f,   0.030841381835560764f,
     0.18703481171909309f,  -0.027983769416859854f, -0.6308807679298589f,
     0.7148465705529157f,  -0.2303778133088965f };

__device__ __forceinline__ int symfold(int idx, int n) {
    idx = (idx < 0) ? (-1 - idx) : idx;
    idx = (idx >= n) ? (2 * n - 1 - idx) : idx;
    return idx;
}

// One DWT level with source in LDS: writes cA (m elems) and cD (m elems).
__device__ __forceinline__ void dwt_lds(const float* __restrict__ src, int n, int m,
                                        float* __restrict__ dstA, float* __restrict__ dstD,
                                        int tid) {
    for (int j = tid; j < m; j += 256) {
        const int base = 2 * j - 6;
        float a = 0.f, d = 0.f;
#pragma unroll
        for (int t = 0; t < 8; ++t) {
            const int idx = symfold(base + t, n);
            const float v = src[idx];
            a = fmaf(v, LO_R[t], a);
            d = fmaf(v, HI_R[t], d);
        }
        dstA[j] = a;
        dstD[j] = d;
    }
}

// Adaptive avg pool of LDS buffer (length n) to 128 means; thread p handles bucket p.
__device__ __forceinline__ void pool_seg(const float* __restrict__ src, int n,
                                         float* __restrict__ dst, int p) {
    const int s = (p * n) >> 7;
    const int e = ((p + 1) * n + 127) >> 7;
    float acc = 0.f;
    for (int t = s; t < e; ++t) acc += src[t];
    dst[p] = acc / (float)(e - s);
}

__global__ __launch_bounds__(256) void dwt_pool_kernel(const float* __restrict__ x,
                                                       float* __restrict__ pooled) {
    __shared__ float bufA[N1];   // cA1 / cA3 / cA5
    __shared__ float bufB[N2];   // cA2 / cA4
    __shared__ float bufD[N2];   // cD scratch per level

    const int tid = threadIdx.x;
    const int row = blockIdx.x;
    const float* __restrict__ xr = x + (size_t)row * SIGLEN;
    float* __restrict__ pr = pooled + (size_t)row * COMB;

    // Level 1: global -> bufA (low-pass only; cD1 never consumed downstream)
    for (int j = tid; j < N1; j += 256) {
        const int base = 2 * j - 6;
        float a = 0.f;
#pragma unroll
        for (int t = 0; t < 8; ++t) {
            const int idx = symfold(base + t, SIGLEN);
            a = fmaf(__ldg(xr + idx), LO_R[t], a);
        }
        bufA[j] = a;
    }
    __syncthreads();

    // Level 2: bufA(8195) -> cA2 in bufB(4101), cD2 in bufD
    dwt_lds(bufA, N1, N2, bufB, bufD, tid);
    __syncthreads();
    if (tid < POOLP) pool_seg(bufD, N2, pr + 4 * POOLP, tid);   // coeffs[4] = cD2
    __syncthreads();

    // Level 3: bufB(4101) -> cA3 in bufA(2054), cD3 in bufD
    dwt_lds(bufB, N2, N3, bufA, bufD, tid);
    __syncthreads();
    if (tid < POOLP) pool_seg(bufD, N3, pr + 3 * POOLP, tid);   // coeffs[3] = cD3
    __syncthreads();

    // Level 4: bufA(2054) -> cA4 in bufB(1030), cD4 in bufD
    dwt_lds(bufA, N3, N4, bufB, bufD, tid);
    __syncthreads();
    if (tid < POOLP) pool_seg(bufD, N4, pr + 2 * POOLP, tid);   // coeffs[2] = cD4
    __syncthreads();

    // Level 5: bufB(1030) -> cA5 in bufA(518), cD5 in bufD
    dwt_lds(bufB, N4, N5, bufA, bufD, tid);
    __syncthreads();
    if (tid < POOLP)       pool_seg(bufA, N5, pr + 0 * POOLP, tid);        // coeffs[0] = cA5
    else                   pool_seg(bufD, N5, pr + 1 * POOLP, tid - POOLP); // coeffs[1] = cD5
}

constexpr int MLP_R = 8;  // rows per block

__global__ __launch_bounds__(256) void mlp_kernel(const float* __restrict__ pooled,
                                                  const float* __restrict__ lw,  // [5][128][128]
                                                  const float* __restrict__ lb,  // [5][128]
                                                  const float* __restrict__ fw,  // [512][640]
                                                  const float* __restrict__ fb,  // [512]
                                                  float* __restrict__ out) {     // [B][512]
    __shared__ float sp[MLP_R][COMB];  // pooled tile
    __shared__ float sc[MLP_R][COMB];  // comb (post level-net ReLU) tile

    const int tid = threadIdx.x;
    const int r0 = blockIdx.x * MLP_R;

    // Load pooled tile (rows are contiguous: flat copy)
    for (int i = tid; i < MLP_R * COMB; i += 256) {
        (&sp[0][0])[i] = pooled[(size_t)r0 * COMB + i];
    }
    __syncthreads();

    // Level nets: comb[r][c] = relu(dot(sp[r][l*128 .. +128], lw[c][:]) + lb[c]), c = l*128+o
    for (int c = tid; c < COMB; c += 256) {
        const float* __restrict__ w = lw + (size_t)c * POOLP;
        const int lbase = (c >> 7) << 7;
        const float bias = lb[c];
        float acc[MLP_R];
#pragma unroll
        for (int r = 0; r < MLP_R; ++r) acc[r] = bias;
        for (int t = 0; t < POOLP; t += 4) {
            const float4 wv = *reinterpret_cast<const float4*>(w + t);
#pragma unroll
            for (int r = 0; r < MLP_R; ++r) {
                const float4 pv = *reinterpret_cast<const float4*>(&sp[r][lbase + t]);
                acc[r] += pv.x * wv.x + pv.y * wv.y + pv.z * wv.z + pv.w * wv.w;
            }
        }
#pragma unroll
        for (int r = 0; r < MLP_R; ++r) sc[r][c] = fmaxf(acc[r], 0.f);
    }
    __syncthreads();

    // Fusion: out[r][j] = relu(dot(sc[r][:], fw[j][:]) + fb[j])
    for (int j = tid; j < OUTD; j += 256) {
        const float* __restrict__ w = fw + (size_t)j * COMB;
        const float bias = fb[j];
        float acc[MLP_R];
#pragma unroll
        for (int r = 0; r < MLP_R; ++r) acc[r] = bias;
        for (int t = 0; t < COMB; t += 4) {
            const float4 wv = *reinterpret_cast<const float4*>(w + t);
#pragma unroll
            for (int r = 0; r < MLP_R; ++r) {
                const float4 cv = *reinterpret_cast<const float4*>(&sc[r][t]);
                acc[r] += cv.x * wv.x + cv.y * wv.y + cv.z * wv.z + cv.w * wv.w;
            }
        }
#pragma unroll
        for (int r = 0; r < MLP_R; ++r) {
            out[(size_t)(r0 + r) * OUTD + j] = fmaxf(acc[r], 0.f);
        }
    }
}

extern "C" void kernel_launch(void* const* d_in, const int* in_sizes, int n_in,
                              void* d_out, int out_size, void* d_ws, size_t ws_size,
                              hipStream_t stream) {
    const float* x  = (const float*)d_in[0];  // [2048][16384]
    const float* lw = (const float*)d_in[1];  // [5][128][128]
    const float* lb = (const float*)d_in[2];  // [5][128]
    const float* fw = (const float*)d_in[3];  // [512][640]
    const float* fb = (const float*)d_in[4];  // [512]
    float* out = (float*)d_out;               // [2048][512]

    float* pooled = (float*)d_ws;             // [2048][640] fp32 = 5.24 MB

    dwt_pool_kernel<<<BATCH, 256, 0, stream>>>(x, pooled);
    mlp_kernel<<<BATCH / MLP_R, 256, 0, stream>>>(pooled, lw, lb, fw, fb, out);
}